// Round 1
// baseline (642.073 us; speedup 1.0000x reference)
//
#include <hip/hip_runtime.h>

// ExpertODEEnsemble: E=8 experts, D=64, H=512, B=32768, IN=D+3=67.
// Strategy:
//  - prep kernel: cast W1(x-part),W2,W3,W4,x to bf16 in ws; fold t/sin/cos
//    columns of W1 into an effective bias b1_eff (those features are
//    batch-constant).
//  - fused kernel: one block = (expert e, 64-row batch tile). Activations
//    (64x512 bf16) kept in LDS in MFMA-A-fragment layout; weights staged
//    (double-buffered) via global_load_lds width=16; 16x16x32 bf16 MFMA;
//    per-expert output combined into d_out with fp32 atomicAdd.
//  - e = blockIdx % 8 -> expert weights resident in one XCD's L2 (~1.15 MB).

typedef unsigned short ushort_t;
typedef __attribute__((ext_vector_type(8))) short short8;
typedef __attribute__((ext_vector_type(4))) float floatx4;

// ws layout (bytes)
#define W1X_OFF 0u         // 8*512*64  bf16 = 524288 B
#define W2_OFF  524288u    // 8*512*512 bf16 = 4 MB
#define W3_OFF  4718592u   // 4 MB
#define W4_OFF  8912896u   // 8*64*512  bf16 = 524288 B
#define XB_OFF  9437184u   // 32768*64  bf16 = 4 MB
#define B1E_OFF 13631488u  // 8*512 fp32 = 16 KB

__device__ __forceinline__ ushort_t f2bf(float f) {
  unsigned int u = __float_as_uint(f);
  u = u + 0x7fffu + ((u >> 16) & 1u);   // round-to-nearest-even
  return (ushort_t)(u >> 16);
}

__device__ __forceinline__ float fast_tanh(float x) {
  // tanh(x) = 1 - 2/(e^{2x}+1); rcp approx is far below bf16 noise.
  float a = __expf(2.0f * x);
  return 1.0f - 2.0f * __builtin_amdgcn_rcpf(a + 1.0f);
}

// async global->LDS, 16B per lane; LDS dest = wave-uniform base + lane*16
__device__ __forceinline__ void ald16(const void* g, void* l) {
  __builtin_amdgcn_global_load_lds((__attribute__((address_space(1))) void*)g,
                                   (__attribute__((address_space(3))) void*)l,
                                   16, 0, 0);
}

__global__ void prep_kernel(const float* __restrict__ t, const float* __restrict__ x,
                            const float* __restrict__ omega,
                            const float* __restrict__ W1, const float* __restrict__ b1,
                            const float* __restrict__ W2, const float* __restrict__ W3,
                            const float* __restrict__ W4, char* __restrict__ ws) {
  ushort_t* W1x = (ushort_t*)(ws + W1X_OFF);
  ushort_t* W2b = (ushort_t*)(ws + W2_OFF);
  ushort_t* W3b = (ushort_t*)(ws + W3_OFF);
  ushort_t* W4b = (ushort_t*)(ws + W4_OFF);
  ushort_t* xb  = (ushort_t*)(ws + XB_OFF);
  float*    b1e = (float*)(ws + B1E_OFF);

  int i = blockIdx.x * 256 + threadIdx.x;
  const int NW1X = 262144, NW2 = 2097152, NW3 = 2097152, NW4 = 262144, NXB = 2097152, NB1E = 4096;
  if (i < NW1X) { W1x[i] = f2bf(W1[(i >> 6) * 67 + (i & 63)]); return; }
  i -= NW1X;
  if (i < NW2) { W2b[i] = f2bf(W2[i]); return; }
  i -= NW2;
  if (i < NW3) { W3b[i] = f2bf(W3[i]); return; }
  i -= NW3;
  if (i < NW4) { W4b[i] = f2bf(W4[i]); return; }
  i -= NW4;
  if (i < NXB) { xb[i] = f2bf(x[i]); return; }
  i -= NXB;
  if (i < NB1E) {
    float tv = t[0];
    int e = i >> 9;
    float om = omega[e];
    b1e[i] = b1[i] + tv * W1[i * 67 + 64] + sinf(om * tv) * W1[i * 67 + 65]
                   + cosf(om * tv) * W1[i * 67 + 66];
  }
}

// stage W[n][kc*32 .. +32) (n = 0..511) into wbuf[buf]: row-major [512][32] bf16
__device__ __forceinline__ void stageW(char* smem, int t, int w,
                                       const ushort_t* W, int ldK, int kc, int buf) {
  char* base = smem + 65536 + buf * 32768 + w * 1024;
#pragma unroll
  for (int i = 0; i < 4; ++i) {
    int g = i * 512 + t;                                // 16B segment id
    ald16(W + (g >> 2) * ldK + kc * 32 + (g & 3) * 8, base + i * 8192);
  }
}

// act_f LDS layout: slot(koct, r) = (koct*64 + r)*16 bytes, koct = k/8,
// each slot holds act[r][koct*8 .. +8) as 8 bf16.  (A-fragment friendly.)
__device__ __forceinline__ void mlp_layer(char* smem, int t, int w, int q, int r15,
                                          int wcol, const ushort_t* W, int ldK,
                                          int nkc, const float* __restrict__ bias) {
  stageW(smem, t, w, W, ldK, 0, 0);
  __syncthreads();   // also orders previous act writes / x fill

  floatx4 acc[4][4];
#pragma unroll
  for (int mt = 0; mt < 4; ++mt)
#pragma unroll
    for (int nt = 0; nt < 4; ++nt)
      acc[mt][nt] = (floatx4){0.f, 0.f, 0.f, 0.f};

  for (int kc = 0; kc < nkc; ++kc) {
    int buf = kc & 1;
    if (kc + 1 < nkc) stageW(smem, t, w, W, ldK, kc + 1, buf ^ 1);
    short8 a[4], b[4];
#pragma unroll
    for (int mt = 0; mt < 4; ++mt)
      a[mt] = *(const short8*)(smem + ((kc * 4 + q) * 64 + mt * 16 + r15) * 16);
#pragma unroll
    for (int nt = 0; nt < 4; ++nt)
      b[nt] = *(const short8*)(smem + 65536 + buf * 32768 +
                               (wcol + nt * 16 + r15) * 64 + q * 16);
#pragma unroll
    for (int mt = 0; mt < 4; ++mt)
#pragma unroll
      for (int nt = 0; nt < 4; ++nt)
        acc[mt][nt] = __builtin_amdgcn_mfma_f32_16x16x32_bf16(a[mt], b[nt], acc[mt][nt], 0, 0, 0);
    __syncthreads();
  }

  // epilogue: bias + tanh -> bf16 -> act_f (this wave owns cols wcol..wcol+63)
#pragma unroll
  for (int nt = 0; nt < 4; ++nt) {
    int c = wcol + nt * 16 + r15;
    float bv = bias[c];
    char* cbase = smem + (c >> 3) * 1024 + (c & 7) * 2;
#pragma unroll
    for (int mt = 0; mt < 4; ++mt) {
#pragma unroll
      for (int i = 0; i < 4; ++i) {
        int r = mt * 16 + q * 4 + i;               // C layout: row=(lane>>4)*4+i
        float v = fast_tanh(acc[mt][nt][i] + bv);
        *(ushort_t*)(cbase + r * 16) = f2bf(v);
      }
    }
  }
  // no barrier: next layer's stage + __syncthreads orders these writes
}

__global__ __launch_bounds__(512, 2) void fused_kernel(
    const char* __restrict__ ws, const float* __restrict__ b2,
    const float* __restrict__ b3, const float* __restrict__ b4,
    const float* __restrict__ ew, float* __restrict__ out) {
  __shared__ char smem[131072];   // 64 KB act_f + 2*32 KB weight staging

  const int t = threadIdx.x;
  const int lane = t & 63;
  const int w = t >> 6;          // wave 0..7
  const int q = lane >> 4;       // lane quad 0..3
  const int r15 = lane & 15;
  const int e = blockIdx.x & 7;                 // expert -> XCD affinity
  const int row0 = (blockIdx.x >> 3) << 6;      // 64-row batch tile
  const int wcol = w << 6;                      // this wave's 64-col N slice

  const ushort_t* xb  = (const ushort_t*)(ws + XB_OFF);
  const ushort_t* W1e = (const ushort_t*)(ws + W1X_OFF) + e * (512 * 64);
  const ushort_t* W2e = (const ushort_t*)(ws + W2_OFF) + e * (512 * 512);
  const ushort_t* W3e = (const ushort_t*)(ws + W3_OFF) + e * (512 * 512);
  const ushort_t* W4e = (const ushort_t*)(ws + W4_OFF) + e * (64 * 512);
  const float*    b1e = (const float*)(ws + B1E_OFF) + e * 512;

  // fill act_f with x tile (k = 0..63): wave w loads octet w of each row
  ald16(xb + (row0 + lane) * 64 + w * 8, smem + w * 1024);

  mlp_layer(smem, t, w, q, r15, wcol, W1e, 64, 2, b1e);
  mlp_layer(smem, t, w, q, r15, wcol, W2e, 512, 16, b2 + e * 512);
  mlp_layer(smem, t, w, q, r15, wcol, W3e, 512, 16, b3 + e * 512);

  // ---- layer 4: dyn = h3 @ W4^T + b4, weighted atomic combine ----
  {
    char* wb = smem + 65536;     // whole W4 tile: [64 n][512 k] bf16 = 64 KB
#pragma unroll
    for (int i = 0; i < 8; ++i) {
      int g = i * 512 + t;
      ald16(W4e + (g >> 6) * 512 + (g & 63) * 8, wb + i * 8192 + w * 1024);
    }
    __syncthreads();

    const int mt = w & 3;        // waves 0-3 / 4-7 split K halves, share mt
    const int kh = w >> 2;
    floatx4 acc4[4];
#pragma unroll
    for (int nt = 0; nt < 4; ++nt) acc4[nt] = (floatx4){0.f, 0.f, 0.f, 0.f};

    for (int kc = kh * 8; kc < kh * 8 + 8; ++kc) {
      short8 a = *(const short8*)(smem + ((kc * 4 + q) * 64 + mt * 16 + r15) * 16);
#pragma unroll
      for (int nt = 0; nt < 4; ++nt) {
        short8 b = *(const short8*)(wb + (nt * 16 + r15) * 1024 + (kc * 4 + q) * 16);
        acc4[nt] = __builtin_amdgcn_mfma_f32_16x16x32_bf16(a, b, acc4[nt], 0, 0, 0);
      }
    }
    __syncthreads();             // all act reads done; act region now dead
    if (w >= 4) {
#pragma unroll
      for (int nt = 0; nt < 4; ++nt)
        *(floatx4*)(smem + ((mt * 4 + nt) * 64 + lane) * 16) = acc4[nt];
    }
    __syncthreads();
    if (w < 4) {
#pragma unroll
      for (int nt = 0; nt < 4; ++nt)
        acc4[nt] += *(const floatx4*)(smem + ((mt * 4 + nt) * 64 + lane) * 16);
#pragma unroll
      for (int nt = 0; nt < 4; ++nt) {
        int c = nt * 16 + r15;
        float bv = b4[e * 64 + c];
#pragma unroll
        for (int i = 0; i < 4; ++i) {
          int row = row0 + mt * 16 + q * 4 + i;
          float val = (acc4[nt][i] + bv) * ew[row * 8 + e];
          atomicAdd(out + row * 64 + c, val);
        }
      }
    }
  }
}

extern "C" void kernel_launch(void* const* d_in, const int* in_sizes, int n_in,
                              void* d_out, int out_size, void* d_ws, size_t ws_size,
                              hipStream_t stream) {
  const float* t  = (const float*)d_in[0];
  const float* x  = (const float*)d_in[1];
  const float* ew = (const float*)d_in[2];
  const float* om = (const float*)d_in[3];
  const float* W1 = (const float*)d_in[4];
  const float* b1 = (const float*)d_in[5];
  const float* W2 = (const float*)d_in[6];
  const float* b2 = (const float*)d_in[7];
  const float* W3 = (const float*)d_in[8];
  const float* b3 = (const float*)d_in[9];
  const float* W4 = (const float*)d_in[10];
  const float* b4 = (const float*)d_in[11];
  char* ws = (char*)d_ws;
  float* out = (float*)d_out;

  (void)in_sizes; (void)n_in; (void)ws_size;

  hipMemsetAsync(out, 0, (size_t)out_size * sizeof(float), stream);
  // total prep elements = 6,819,840 = 26640 * 256 exactly
  prep_kernel<<<26640, 256, 0, stream>>>(t, x, om, W1, b1, W2, W3, W4, ws);
  fused_kernel<<<4096, 512, 0, stream>>>(ws, b2, b3, b4, ew, out);
}

// Round 2
// 602.079 us; speedup vs baseline: 1.0664x; 1.0664x over previous
//
#include <hip/hip_runtime.h>

// ExpertODEEnsemble: E=8, D=64, H=512, B=32768.
// R2 restructure: weights streamed L2->VGPR in MFMA-A order (no LDS staging),
// acts in LDS as B-fragments (stride-1 1KB reads), 32x32x16 bf16 MFMA,
// operand-flipped so epilogue writes are 8B packed (C rows = next layer's K).
// LDS 66KB -> 2 blocks/CU.

typedef unsigned short ushort_t;
typedef unsigned long long u64;
typedef __attribute__((ext_vector_type(8))) short short8;
typedef __attribute__((ext_vector_type(4))) float floatx4;
typedef __attribute__((ext_vector_type(16))) float floatx16;

// ws layout (bytes)
#define W1A_OFF 0u          // 8*512*64  bf16 = 512 KB   [e][kc0..3][o0..15][lane][j]
#define W2A_OFF 524288u     // 8*512*512 bf16 = 4 MB     [e][kc0..31][o0..15][lane][j]
#define W3A_OFF 4718592u    // 4 MB
#define W4A_OFF 8912896u    // 8*64*512  bf16 = 512 KB   [e][kc0..31][o0..1][lane][j]
#define XB_OFF  9437184u    // 32768*64 bf16 = 4 MB, row-major
#define B1E_OFF 13631488u   // 8*512 fp32

__device__ __forceinline__ ushort_t f2bf(float f) {
  unsigned int u = __float_as_uint(f);
  u = u + 0x7fffu + ((u >> 16) & 1u);   // RNE
  return (ushort_t)(u >> 16);
}

__device__ __forceinline__ float fast_tanh(float x) {
  float a = __expf(2.0f * x);
  return 1.0f - 2.0f * __builtin_amdgcn_rcpf(a + 1.0f);
}

__device__ __forceinline__ void ald16(const void* g, void* l) {
  __builtin_amdgcn_global_load_lds((__attribute__((address_space(1))) void*)g,
                                   (__attribute__((address_space(3))) void*)l,
                                   16, 0, 0);
}

__device__ __forceinline__ floatx16 mfma32(short8 a, short8 b, floatx16 c) {
  return __builtin_amdgcn_mfma_f32_32x32x16_bf16(a, b, c, 0, 0, 0);
}

// ---------------- prep: cast + permute into A-fragment streaming order -------
__global__ void prep_kernel(const float* __restrict__ t, const float* __restrict__ x,
                            const float* __restrict__ omega,
                            const float* __restrict__ W1, const float* __restrict__ b1,
                            const float* __restrict__ W2, const float* __restrict__ W3,
                            const float* __restrict__ W4, char* __restrict__ ws) {
  int i = blockIdx.x * 256 + threadIdx.x;
  if (i < 262144) {                      // W1A (K=64: kc 0..3)
    int e = i >> 15, r = i & 32767;
    int j = r & 7, g = r >> 3, lane = g & 63, og = g >> 6;
    int o = og & 15, kc = og >> 4;
    int out = o * 32 + (lane & 31);
    int k = kc * 16 + (lane >> 5) * 8 + j;
    ((ushort_t*)(ws + W1A_OFF))[i] = f2bf(W1[(e * 512 + out) * 67 + k]);
    return;
  }
  i -= 262144;
  if (i < 2097152) {                     // W2A
    int e = i >> 18, r = i & 262143;
    int j = r & 7, g = r >> 3, lane = g & 63, og = g >> 6;
    int o = og & 15, kc = og >> 4;
    int out = o * 32 + (lane & 31);
    int k = kc * 16 + (lane >> 5) * 8 + j;
    ((ushort_t*)(ws + W2A_OFF))[i] = f2bf(W2[(e * 512 + out) * 512 + k]);
    return;
  }
  i -= 2097152;
  if (i < 2097152) {                     // W3A
    int e = i >> 18, r = i & 262143;
    int j = r & 7, g = r >> 3, lane = g & 63, og = g >> 6;
    int o = og & 15, kc = og >> 4;
    int out = o * 32 + (lane & 31);
    int k = kc * 16 + (lane >> 5) * 8 + j;
    ((ushort_t*)(ws + W3A_OFF))[i] = f2bf(W3[(e * 512 + out) * 512 + k]);
    return;
  }
  i -= 2097152;
  if (i < 262144) {                      // W4A (out=64: o 0..1)
    int e = i >> 15, r = i & 32767;
    int j = r & 7, g = r >> 3, lane = g & 63, og = g >> 6;
    int o = og & 1, kc = og >> 1;
    int out = o * 32 + (lane & 31);
    int k = kc * 16 + (lane >> 5) * 8 + j;
    ((ushort_t*)(ws + W4A_OFF))[i] = f2bf(W4[(e * 64 + out) * 512 + k]);
    return;
  }
  i -= 262144;
  if (i < 2097152) { ((ushort_t*)(ws + XB_OFF))[i] = f2bf(x[i]); return; }
  i -= 2097152;
  if (i < 4096) {                        // b1_eff (fold t/sin/cos columns)
    float tv = t[0];
    int e = i >> 9;
    float om = omega[e];
    ((float*)(ws + B1E_OFF))[i] = b1[i] + tv * W1[i * 67 + 64]
        + sinf(om * tv) * W1[i * 67 + 65] + cosf(om * tv) * W1[i * 67 + 66];
  }
}

// act LDS layout: granule f(b_row, koct) = (koct>>1)*132 + (b_row>>5)*64
//                 + (koct&1)*32 + (b_row&31), 16B each (8 bf16 along k).
// B-frag read for (nt, kc): base + lane -> stride-1 1KB. kc pad=4 granules.

__device__ __forceinline__ void mlp_layer(char* __restrict__ smem, int lane, int w,
                                          const ushort_t* __restrict__ WA, int nkc,
                                          const float* __restrict__ bias) {
  const short8* A0 = (const short8*)WA + (w * 2) * 64 + lane;  // granule units
  floatx16 acc[2][2] = {};
  short8 a0 = A0[0], a1 = A0[64];
#pragma unroll 2
  for (int kc = 0; kc < nkc; ++kc) {
    short8 a0c = a0, a1c = a1;
    if (kc + 1 < nkc) { a0 = A0[(kc + 1) * 1024]; a1 = A0[(kc + 1) * 1024 + 64]; }
    short8 b0 = *(const short8*)(smem + ((kc * 132 + lane) << 4));
    short8 b1 = *(const short8*)(smem + ((kc * 132 + 64 + lane) << 4));
    acc[0][0] = mfma32(a0c, b0, acc[0][0]);
    acc[0][1] = mfma32(a0c, b1, acc[0][1]);
    acc[1][0] = mfma32(a1c, b0, acc[1][0]);
    acc[1][1] = mfma32(a1c, b1, acc[1][1]);
  }
  __syncthreads();                       // all B reads of this layer complete
  const int q1 = lane >> 5, r31 = lane & 31;
#pragma unroll
  for (int ol = 0; ol < 2; ++ol) {
    const int o_abs = w * 2 + ol;
#pragma unroll
    for (int g = 0; g < 4; ++g) {
      const int koct = o_abs * 4 + g;    // C rows m = o_abs*32 + 8g + 4q1 + rr
      floatx4 bv = *(const floatx4*)(bias + o_abs * 32 + g * 8 + q1 * 4);
#pragma unroll
      for (int nt = 0; nt < 2; ++nt) {
        u64 pk = 0;
#pragma unroll
        for (int rr = 0; rr < 4; ++rr) {
          float v = fast_tanh(acc[ol][nt][g * 4 + rr] + bv[rr]);
          pk |= (u64)f2bf(v) << (rr * 16);
        }
        int f = (koct >> 1) * 132 + nt * 64 + (koct & 1) * 32 + r31;
        *(u64*)(smem + f * 16 + q1 * 8) = pk;
      }
    }
  }
  __syncthreads();                       // act visible to next layer
}

__global__ __launch_bounds__(512, 4) void fused_kernel(
    const char* __restrict__ ws, const float* __restrict__ b2,
    const float* __restrict__ b3, const float* __restrict__ b4,
    const float* __restrict__ ew, float* __restrict__ out) {
  __shared__ char smem[67584];           // 32 kc * 132 granules * 16B
  const int t = threadIdx.x, lane = t & 63, w = t >> 6;
  const int q1 = lane >> 5, r31 = lane & 31;
  const int e = blockIdx.x & 7;          // expert -> XCD L2 affinity
  const int row0 = (blockIdx.x >> 3) << 6;

  // stage x tile (K=64 -> kc 0..3) into act region, wave-uniform-base + lane*16
  const ushort_t* xb = (const ushort_t*)(ws + XB_OFF);
  ald16(xb + (row0 + (w & 1) * 32 + r31) * 64 + ((w >> 1) * 2 + q1) * 8,
        smem + ((w >> 1) * 132 + (w & 1) * 64) * 16);
  __syncthreads();

  mlp_layer(smem, lane, w, (const ushort_t*)(ws + W1A_OFF) + e * 32768, 4,
            (const float*)(ws + B1E_OFF) + e * 512);
  mlp_layer(smem, lane, w, (const ushort_t*)(ws + W2A_OFF) + e * 262144, 32,
            b2 + e * 512);
  mlp_layer(smem, lane, w, (const ushort_t*)(ws + W3A_OFF) + e * 262144, 32,
            b3 + e * 512);

  // ---- layer 4: M=64, N=64; wave w -> tile (o=w&1, nt=(w>>1)&1), K-half w>>2
  {
    const int o = w & 1, nt = (w >> 1) & 1, kh = w >> 2;
    const short8* A = (const short8*)((const ushort_t*)(ws + W4A_OFF) + e * 32768);
    floatx16 acc = {};
    short8 a = A[((kh * 16) * 2 + o) * 64 + lane];
    for (int kc = kh * 16; kc < kh * 16 + 16; ++kc) {
      short8 ac = a;
      if (kc + 1 < kh * 16 + 16) a = A[((kc + 1) * 2 + o) * 64 + lane];
      short8 b = *(const short8*)(smem + ((kc * 132 + nt * 64 + lane) << 4));
      acc = mfma32(ac, b, acc);
    }
    __syncthreads();                     // act region now dead
    if (w >= 4) {
#pragma unroll
      for (int i = 0; i < 4; ++i) {
        floatx4 p = {acc[i * 4 + 0], acc[i * 4 + 1], acc[i * 4 + 2], acc[i * 4 + 3]};
        *(floatx4*)(smem + (w - 4) * 4096 + lane * 64 + i * 16) = p;
      }
    }
    __syncthreads();
    if (w < 4) {
#pragma unroll
      for (int i = 0; i < 4; ++i) {
        floatx4 p = *(const floatx4*)(smem + w * 4096 + lane * 64 + i * 16);
        acc[i * 4 + 0] += p[0]; acc[i * 4 + 1] += p[1];
        acc[i * 4 + 2] += p[2]; acc[i * 4 + 3] += p[3];
      }
      const int row = row0 + nt * 32 + r31;
      const float sc = ew[row * 8 + e];
#pragma unroll
      for (int g = 0; g < 4; ++g) {
        floatx4 bv = *(const floatx4*)(b4 + e * 64 + o * 32 + g * 8 + q1 * 4);
#pragma unroll
        for (int rr = 0; rr < 4; ++rr) {
          int m = o * 32 + g * 8 + q1 * 4 + rr;
          atomicAdd(out + row * 64 + m, (acc[g * 4 + rr] + bv[rr]) * sc);
        }
      }
    }
  }
}

extern "C" void kernel_launch(void* const* d_in, const int* in_sizes, int n_in,
                              void* d_out, int out_size, void* d_ws, size_t ws_size,
                              hipStream_t stream) {
  const float* t  = (const float*)d_in[0];
  const float* x  = (const float*)d_in[1];
  const float* ew = (const float*)d_in[2];
  const float* om = (const float*)d_in[3];
  const float* W1 = (const float*)d_in[4];
  const float* b1 = (const float*)d_in[5];
  const float* W2 = (const float*)d_in[6];
  const float* b2 = (const float*)d_in[7];
  const float* W3 = (const float*)d_in[8];
  const float* b3 = (const float*)d_in[9];
  const float* W4 = (const float*)d_in[10];
  const float* b4 = (const float*)d_in[11];
  char* ws = (char*)d_ws;
  float* out = (float*)d_out;
  (void)in_sizes; (void)n_in; (void)ws_size;

  hipMemsetAsync(out, 0, (size_t)out_size * sizeof(float), stream);
  // total prep elements = 6,819,840 = 26640 * 256 exactly
  prep_kernel<<<26640, 256, 0, stream>>>(t, x, om, W1, b1, W2, W3, W4, ws);
  fused_kernel<<<4096, 512, 0, stream>>>(ws, b2, b3, b4, ew, out);
}